// Round 6
// baseline (1283.524 us; speedup 1.0000x reference)
//
#include <hip/hip_runtime.h>
#include <math.h>

// ---------------- problem constants ----------------
#define ND 2048
#define NS 1024
#define DIN 768
#define DOUT 64
#define NSTEPS 20
static constexpr float BLUR2 = 0.05f * 0.05f; // blur^p, p=2

// ---------------- ws layout (float offsets) ----------------
#define OFF_X     0u              // 3072*64 = 196608
#define OFF_NRM   196608u         // 3072 (0.5*||row||^2), nx then ny (ends 199680)
#define OFF_MM    199680u         // 128 uints: 64 min keys | 64 max keys (dedicated!
                                  // must NOT alias C regions - build_cost runs after
                                  // proj but BEFORE the fused kernel reads these)
#define OFF_CXY   212032u         // 2048*1024
#define OFF_CYX   2309184u        // 1024*2048
#define OFF_CXX   4406336u        // 2048*2048
#define OFF_CYY   8600640u        // 1024*1024 (end 9649216)
// per-generation potential buffers: pots[g], g=0..21, 6144 floats each
// [f_ab 2048 | g_ab 1024 | f_aa 2048 | g_bb 1024]
#define OFF_POTS  9649216u
#define POT_STRIDE 6144u
// barrier area (uints): 64 arrival lines (stride 64) + 32 gen lines (stride 64)
#define OFF_BARRIER (9649216u + 22u * 6144u)   // = 9784384, 6144 uints
#define NBLK 1024   // fused kernel grid (4 blocks/CU -> co-resident by construction)

// monotone float<->uint key encoding (order-preserving for atomicMin/Max)
__device__ inline unsigned fkey(float f) {
  const unsigned b = __float_as_uint(f);
  return (b & 0x80000000u) ? ~b : (b | 0x80000000u);
}
__device__ inline float funkey(unsigned k) {
  const unsigned b = (k & 0x80000000u) ? (k & 0x7FFFFFFFu) : ~k;
  return __uint_as_float(b);
}

// ---------------- kernel 0: seed min/max keys + zero barrier area ----------------
__global__ __launch_bounds__(256) void init_mm(float* __restrict__ ws) {
  const int t = threadIdx.x;
  unsigned* mm = reinterpret_cast<unsigned*>(ws + OFF_MM);
  if (t < 64)       mm[t] = 0xFFFFFFFFu; // min keys = +inf
  else if (t < 128) mm[t] = 0u;          // max keys = -inf
  unsigned* bar = reinterpret_cast<unsigned*>(ws + OFF_BARRIER);
  for (int i = t; i < 6144; i += 256) bar[i] = 0u;
}

// ---------------- kernel 1: projection (K-split) + row sqnorms + atomic min/max ----
__global__ __launch_bounds__(256) void proj_kernel(const float* __restrict__ d,
                                                   const float* __restrict__ s,
                                                   const float* __restrict__ M,
                                                   float* __restrict__ ws) {
  const int w    = threadIdx.x >> 6;
  const int lane = threadIdx.x & 63;
  const int r0   = blockIdx.x * 4;

  const float* base;
  if (r0 < ND) base = d + (size_t)r0 * DIN;
  else         base = s + (size_t)(r0 - ND) * DIN;

  const float4* s0 = reinterpret_cast<const float4*>(base + 0 * DIN + w * 192);
  const float4* s1 = reinterpret_cast<const float4*>(base + 1 * DIN + w * 192);
  const float4* s2 = reinterpret_cast<const float4*>(base + 2 * DIN + w * 192);
  const float4* s3 = reinterpret_cast<const float4*>(base + 3 * DIN + w * 192);
  const float* Mw = M + (size_t)(w * 192) * DOUT + lane;

  float a0 = 0.f, a1 = 0.f, a2 = 0.f, a3 = 0.f;
#pragma unroll 4
  for (int kk = 0; kk < 48; ++kk) {
    const float4 r0v = s0[kk];
    const float4 r1v = s1[kk];
    const float4 r2v = s2[kk];
    const float4 r3v = s3[kk];
    const float m0 = Mw[(kk * 4 + 0) * DOUT];
    const float m1 = Mw[(kk * 4 + 1) * DOUT];
    const float m2 = Mw[(kk * 4 + 2) * DOUT];
    const float m3 = Mw[(kk * 4 + 3) * DOUT];
    a0 = fmaf(r0v.x, m0, a0); a0 = fmaf(r0v.y, m1, a0);
    a0 = fmaf(r0v.z, m2, a0); a0 = fmaf(r0v.w, m3, a0);
    a1 = fmaf(r1v.x, m0, a1); a1 = fmaf(r1v.y, m1, a1);
    a1 = fmaf(r1v.z, m2, a1); a1 = fmaf(r1v.w, m3, a1);
    a2 = fmaf(r2v.x, m0, a2); a2 = fmaf(r2v.y, m1, a2);
    a2 = fmaf(r2v.z, m2, a2); a2 = fmaf(r2v.w, m3, a2);
    a3 = fmaf(r3v.x, m0, a3); a3 = fmaf(r3v.y, m1, a3);
    a3 = fmaf(r3v.z, m2, a3); a3 = fmaf(r3v.w, m3, a3);
  }

  __shared__ float part[4][4][64];
  part[w][0][lane] = a0;
  part[w][1][lane] = a1;
  part[w][2][lane] = a2;
  part[w][3][lane] = a3;
  __syncthreads();

  if (w == 0) {
    const float f0 = part[0][0][lane] + part[1][0][lane] + part[2][0][lane] + part[3][0][lane];
    const float f1 = part[0][1][lane] + part[1][1][lane] + part[2][1][lane] + part[3][1][lane];
    const float f2 = part[0][2][lane] + part[1][2][lane] + part[2][2][lane] + part[3][2][lane];
    const float f3 = part[0][3][lane] + part[1][3][lane] + part[2][3][lane] + part[3][3][lane];

    float* xy = ws + OFF_X;
    xy[(size_t)(r0 + 0) * DOUT + lane] = f0;
    xy[(size_t)(r0 + 1) * DOUT + lane] = f1;
    xy[(size_t)(r0 + 2) * DOUT + lane] = f2;
    xy[(size_t)(r0 + 3) * DOUT + lane] = f3;

    const float mn4 = fminf(fminf(f0, f1), fminf(f2, f3));
    const float mx4 = fmaxf(fmaxf(f0, f1), fmaxf(f2, f3));
    unsigned* mm = reinterpret_cast<unsigned*>(ws + OFF_MM);
    atomicMin(mm + lane, fkey(mn4));
    atomicMax(mm + 64 + lane, fkey(mx4));

    float n0 = f0 * f0, n1 = f1 * f1, n2 = f2 * f2, n3 = f3 * f3;
#pragma unroll
    for (int off = 32; off > 0; off >>= 1) {
      n0 += __shfl_xor(n0, off, 64);
      n1 += __shfl_xor(n1, off, 64);
      n2 += __shfl_xor(n2, off, 64);
      n3 += __shfl_xor(n3, off, 64);
    }
    if (lane == 0) {
      float* nrm = ws + OFF_NRM;
      nrm[r0 + 0] = 0.5f * n0;
      nrm[r0 + 1] = 0.5f * n1;
      nrm[r0 + 2] = 0.5f * n2;
      nrm[r0 + 3] = 0.5f * n3;
    }
  }
}

// ---------------- kernel 2: build cost matrices ----------------
__global__ __launch_bounds__(256) void build_cost(float* __restrict__ ws) {
  const int b = blockIdx.x;
  const int tid = threadIdx.x;

  const float* A;
  const float* B;
  const float* nA;
  const float* nB;
  float* Cout;
  float* CoutT = nullptr;
  int ldc, ldcT = 0, ti, tj;

  const float* x = ws + OFF_X;
  const float* y = ws + OFF_X + (size_t)ND * DOUT;
  const float* nx = ws + OFF_NRM;
  const float* ny = ws + OFF_NRM + ND;

  if (b < 512) {
    ti = b >> 4; tj = b & 15;
    A = x; B = y; nA = nx; nB = ny;
    Cout = ws + OFF_CXY; ldc = NS;
    CoutT = ws + OFF_CYX; ldcT = ND;
  } else if (b < 1536) {
    const int bb = b - 512;
    ti = bb >> 5; tj = bb & 31;
    A = x; B = x; nA = nx; nB = nx;
    Cout = ws + OFF_CXX; ldc = ND;
  } else {
    const int bb = b - 1536;
    ti = bb >> 4; tj = bb & 15;
    A = y; B = y; nA = ny; nB = ny;
    Cout = ws + OFF_CYY; ldc = NS;
  }

  __shared__ float Ast[64][68];
  __shared__ float Bst[64][68];

  for (int idx = tid; idx < 64 * 16; idx += 256) {
    const int row = idx >> 4;
    const int c4 = idx & 15;
    const float4 a = reinterpret_cast<const float4*>(A + (size_t)(ti * 64 + row) * DOUT)[c4];
    Ast[c4 * 4 + 0][row] = a.x;
    Ast[c4 * 4 + 1][row] = a.y;
    Ast[c4 * 4 + 2][row] = a.z;
    Ast[c4 * 4 + 3][row] = a.w;
    const float4 bv = reinterpret_cast<const float4*>(B + (size_t)(tj * 64 + row) * DOUT)[c4];
    Bst[c4 * 4 + 0][row] = bv.x;
    Bst[c4 * 4 + 1][row] = bv.y;
    Bst[c4 * 4 + 2][row] = bv.z;
    Bst[c4 * 4 + 3][row] = bv.w;
  }
  __syncthreads();

  const int tr = tid >> 4;
  const int tc = tid & 15;
  float acc[4][4] = {};
#pragma unroll 4
  for (int k = 0; k < 64; ++k) {
    float av[4], bv[4];
#pragma unroll
    for (int i = 0; i < 4; ++i) av[i] = Ast[k][tr * 4 + i];
#pragma unroll
    for (int j = 0; j < 4; ++j) bv[j] = Bst[k][tc * 4 + j];
#pragma unroll
    for (int i = 0; i < 4; ++i)
#pragma unroll
      for (int j = 0; j < 4; ++j) acc[i][j] = fmaf(av[i], bv[j], acc[i][j]);
  }

  float na[4], nb[4];
#pragma unroll
  for (int i = 0; i < 4; ++i) na[i] = nA[ti * 64 + tr * 4 + i];
#pragma unroll
  for (int j = 0; j < 4; ++j) nb[j] = nB[tj * 64 + tc * 4 + j];

#pragma unroll
  for (int i = 0; i < 4; ++i) {
    const int gi = ti * 64 + tr * 4 + i;
    float4 cv;
    cv.x = na[i] + nb[0] - acc[i][0];
    cv.y = na[i] + nb[1] - acc[i][1];
    cv.z = na[i] + nb[2] - acc[i][2];
    cv.w = na[i] + nb[3] - acc[i][3];
    reinterpret_cast<float4*>(Cout + (size_t)gi * ldc + tj * 64 + tc * 4)[0] = cv;
    if (CoutT) {
      const int gj = tj * 64 + tc * 4;
      CoutT[(size_t)(gj + 0) * ldcT + gi] = cv.x;
      CoutT[(size_t)(gj + 1) * ldcT + gi] = cv.y;
      CoutT[(size_t)(gj + 2) * ldcT + gi] = cv.z;
      CoutT[(size_t)(gj + 3) * ldcT + gi] = cv.w;
    }
  }
}

// ---------------- softmin row primitive ----------------
// f_i = -max_j(v) - eps*log( (1/LEN) * sum_j exp((v_j - max)/eps) ), v_j = pot_j - C_ij
template <int LEN, bool USEPOT>
__device__ inline float softmin_row(const float* __restrict__ Crow,
                                    const float* __restrict__ pin,
                                    int lane, float eps, float inv_eps) {
  constexpr int NK = LEN / 256;
  float v[NK * 4];
  float m = -3.4e38f;
#pragma unroll
  for (int k = 0; k < NK; ++k) {
    const float4 c4 = reinterpret_cast<const float4*>(Crow)[k * 64 + lane];
    float4 p4 = make_float4(0.f, 0.f, 0.f, 0.f);
    if (USEPOT) p4 = reinterpret_cast<const float4*>(pin)[k * 64 + lane];
    v[4 * k + 0] = p4.x - c4.x;
    v[4 * k + 1] = p4.y - c4.y;
    v[4 * k + 2] = p4.z - c4.z;
    v[4 * k + 3] = p4.w - c4.w;
    m = fmaxf(m, fmaxf(fmaxf(v[4 * k + 0], v[4 * k + 1]), fmaxf(v[4 * k + 2], v[4 * k + 3])));
  }
#pragma unroll
  for (int off = 32; off > 0; off >>= 1) m = fmaxf(m, __shfl_xor(m, off, 64));
  float ssum = 0.f;
#pragma unroll
  for (int k = 0; k < NK * 4; ++k) ssum += __expf((v[k] - m) * inv_eps);
#pragma unroll
  for (int off = 32; off > 0; off >>= 1) ssum += __shfl_xor(ssum, off, 64);
  return -m - eps * __logf(ssum * (1.0f / (float)LEN));
}

// ---------------- fused sinkhorn: one job ----------------
// Job table: [0,2048) f_ab rows (C_xy, pin=g_ab); [2048,3072) g_ab rows (C_yx, pin=f_ab);
// [3072,5120) f_aa rows (C_xx); [5120,6144) g_bb rows (C_yy).
template <bool USEPOT>
__device__ inline void run_job(const float* __restrict__ ws, const float* __restrict__ potIn,
                               float* __restrict__ potOut, int j, float eps, float inv_eps,
                               bool avg, int lane) {
  const float* Crow;
  const float* pin;
  int outIdx, len;
  if (j < 2048)      { Crow = ws + OFF_CXY + (size_t)j * NS;                        pin = potIn + 2048; outIdx = j;        len = NS; }
  else if (j < 3072) { const int r = j - 2048; Crow = ws + OFF_CYX + (size_t)r * ND; pin = potIn;        outIdx = 2048 + r; len = ND; }
  else if (j < 5120) { const int r = j - 3072; Crow = ws + OFF_CXX + (size_t)r * ND; pin = potIn + 3072; outIdx = 3072 + r; len = ND; }
  else               { const int r = j - 5120; Crow = ws + OFF_CYY + (size_t)r * NS; pin = potIn + 5120; outIdx = 5120 + r; len = NS; }

  float f = (len == NS) ? softmin_row<NS, USEPOT>(Crow, pin, lane, eps, inv_eps)
                        : softmin_row<ND, USEPOT>(Crow, pin, lane, eps, inv_eps);
  if (avg) f = 0.5f * (potIn[outIdx] + f);
  if (lane == 0)
    __hip_atomic_store(&potOut[outIdx], f, __ATOMIC_RELAXED, __HIP_MEMORY_SCOPE_AGENT);
}

// ---------------- device-wide barrier (monotone counters, hierarchical) ----------------
// 64 arrival lines (stride 64 uints), detector = wave 0 of block 0, 32 gen fan-out lines.
__device__ inline void gbarrier(unsigned* __restrict__ bar, unsigned k) {
  __syncthreads();
  if (threadIdx.x == 0) {
    unsigned* cnt = bar + (size_t)(blockIdx.x & 63) * 64;
    __hip_atomic_fetch_add(cnt, 1u, __ATOMIC_RELEASE, __HIP_MEMORY_SCOPE_AGENT);
  }
  if (blockIdx.x == 0) {
    if (threadIdx.x < 64) {
      const unsigned target = (unsigned)NBLK * k;
      for (;;) {
        unsigned v = __hip_atomic_load(bar + (size_t)threadIdx.x * 64,
                                       __ATOMIC_ACQUIRE, __HIP_MEMORY_SCOPE_AGENT);
        unsigned sum = v;
#pragma unroll
        for (int off = 32; off > 0; off >>= 1)
          sum += (unsigned)__shfl_xor((int)sum, off, 64);
        if (sum >= target) break;
        __builtin_amdgcn_s_sleep(8);
      }
      if (threadIdx.x < 32)
        __hip_atomic_store(bar + 4096 + (size_t)threadIdx.x * 64, k,
                           __ATOMIC_RELEASE, __HIP_MEMORY_SCOPE_AGENT);
    }
  } else {
    if (threadIdx.x == 0) {
      unsigned* gen = bar + 4096 + (size_t)(blockIdx.x & 31) * 64;
      while (__hip_atomic_load(gen, __ATOMIC_ACQUIRE, __HIP_MEMORY_SCOPE_AGENT) < k)
        __builtin_amdgcn_s_sleep(8);
    }
  }
  __syncthreads();
}

// ---------------- kernel 3: fused sinkhorn (init + 20 steps + final + epilogue) ----
// 1024 blocks x 256. wave = blockIdx*4 + (tid>>6); waves 0..2047 take a second job.
__global__ __launch_bounds__(256, 4) void sinkhorn_fused(float* __restrict__ ws,
                                                         float* __restrict__ out) {
  const int w    = threadIdx.x >> 6;
  const int lane = threadIdx.x & 63;
  const int wave = blockIdx.x * 4 + w;
  float* pots = ws + OFF_POTS;
  unsigned* bar = reinterpret_cast<unsigned*>(ws + OFF_BARRIER);

  // diameter^2 from mm keys (written by proj_kernel, prior dispatch; dedicated slot)
  float diam2;
  {
    const unsigned* mm = reinterpret_cast<const unsigned*>(ws + OFF_MM);
    const float mn = funkey(mm[lane]);
    const float mx = funkey(mm[64 + lane]);
    const float rng = mx - mn;
    float p = rng * rng;
#pragma unroll
    for (int off = 32; off > 0; off >>= 1) p += __shfl_xor(p, off, 64);
    diam2 = p;
  }

  const int j0 = wave;
  const int j1 = (wave < 2048) ? 4096 + wave : -1;
  unsigned bk = 0;

  // ---- init: pots[0], eps0 = max(diam2, blur^2), no pot, no avg
  {
    const float eps = fmaxf(diam2, BLUR2);
    const float ie = 1.0f / eps;
    run_job<false>(ws, pots, pots, j0, eps, ie, false, lane);
    if (j1 >= 0) run_job<false>(ws, pots, pots, j1, eps, ie, false, lane);
  }
  gbarrier(bar, ++bk);

  // ---- 20 scan steps: pots[t] -> pots[t+1], averaged
  for (int t = 0; t < NSTEPS; ++t) {
    const float eps = fmaxf(ldexpf(diam2, -2 * t), BLUR2);
    const float ie = 1.0f / eps;
    const float* pin  = pots + (size_t)t * POT_STRIDE;
    float*       pout = pots + (size_t)(t + 1) * POT_STRIDE;
    run_job<true>(ws, pin, pout, j0, eps, ie, true, lane);
    if (j1 >= 0) run_job<true>(ws, pin, pout, j1, eps, ie, true, lane);
    gbarrier(bar, ++bk);
  }

  // ---- final extrapolation at eps = blur^2
  {
    const float eps = BLUR2;
    const float ie = 1.0f / eps;
    const float* pin  = pots + (size_t)NSTEPS * POT_STRIDE;        // pots[20]
    float*       pout = pots + (size_t)(NSTEPS + 1) * POT_STRIDE;  // pots[21]
    // A: f_ab, f_aa, g_bb (skip g_ab jobs)
    if (j0 < 2048 || j0 >= 3072) run_job<true>(ws, pin, pout, j0, eps, ie, false, lane);
    if (j1 >= 0)                 run_job<true>(ws, pin, pout, j1, eps, ie, false, lane);
    gbarrier(bar, ++bk);
    // B: g_ab from the NEW f_ab (in/out pots[21])
    if (j0 >= 2048 && j0 < 3072) run_job<true>(ws, pout, pout, j0, eps, ie, false, lane);
    gbarrier(bar, ++bk);
  }

  // ---- epilogue: block 0 computes exp(-loss)
  if (blockIdx.x == 0) {
    const float* pot = pots + (size_t)(NSTEPS + 1) * POT_STRIDE;
    const int tid = threadIdx.x;
    float s1 = 0.f, s2 = 0.f;
    for (int i = tid; i < ND; i += 256) s1 += pot[i] - pot[3072 + i];
    for (int j = tid; j < NS; j += 256) s2 += pot[2048 + j] - pot[5120 + j];
    float part = s1 * (1.0f / (float)ND) + s2 * (1.0f / (float)NS);
#pragma unroll
    for (int off = 32; off > 0; off >>= 1) part += __shfl_xor(part, off, 64);
    __shared__ float sp[4];
    if ((tid & 63) == 0) sp[tid >> 6] = part;
    __syncthreads();
    if (tid == 0) out[0] = expf(-(sp[0] + sp[1] + sp[2] + sp[3]));
  }
}

// ---------------- host ----------------
extern "C" void kernel_launch(void* const* d_in, const int* in_sizes, int n_in,
                              void* d_out, int out_size, void* d_ws, size_t ws_size,
                              hipStream_t stream) {
  const float* d = (const float*)d_in[0];
  const float* s = (const float*)d_in[1];
  const float* M = (const float*)d_in[2];
  float* out = (float*)d_out;
  float* ws = (float*)d_ws;

  init_mm<<<1, 256, 0, stream>>>(ws);
  proj_kernel<<<768, 256, 0, stream>>>(d, s, M, ws);
  build_cost<<<1792, 256, 0, stream>>>(ws);
  sinkhorn_fused<<<NBLK, 256, 0, stream>>>(ws, out);
}

// Round 7
// 445.292 us; speedup vs baseline: 2.8824x; 2.8824x over previous
//
#include <hip/hip_runtime.h>
#include <math.h>

// ---------------- problem constants ----------------
#define ND 2048
#define NS 1024
#define DIN 768
#define DOUT 64
#define NSTEPS 20
static constexpr float BLUR2 = 0.05f * 0.05f; // blur^p, p=2

// ---------------- ws layout (float offsets) ----------------
#define OFF_X     0u              // 3072*64 = 196608
#define OFF_NRM   196608u         // 3072 (0.5*||row||^2), nx then ny (ends 199680)
#define OFF_MM    199680u         // 128 uints: 64 min keys | 64 max keys (dedicated slot)
#define OFF_CXY   212032u         // 2048*1024
#define OFF_CYX   2309184u        // 1024*2048
#define OFF_CXX   4406336u        // 2048*2048
#define OFF_CYY   8600640u        // 1024*1024 (end 9649216)
// per-generation potential buffers: pots[g], g=0..21, 6144 floats each
// [f_ab 2048 | g_ab 1024 | f_aa 2048 | g_bb 1024]
#define OFF_POTS  9649216u
#define POT_STRIDE 6144u
// barrier area (uints): 64 arrival lines (stride 64) + 32 gen lines (stride 64)
#define OFF_BARRIER (9649216u + 22u * 6144u)   // = 9784384, 6144 uints
#define NBLK 1024   // fused kernel grid (4 blocks/CU -> co-resident by construction)

// monotone float<->uint key encoding (order-preserving for atomicMin/Max)
__device__ inline unsigned fkey(float f) {
  const unsigned b = __float_as_uint(f);
  return (b & 0x80000000u) ? ~b : (b | 0x80000000u);
}
__device__ inline float funkey(unsigned k) {
  const unsigned b = (k & 0x80000000u) ? (k & 0x7FFFFFFFu) : ~k;
  return __uint_as_float(b);
}

// ---------------- kernel 0: seed min/max keys + zero barrier area ----------------
__global__ __launch_bounds__(256) void init_mm(float* __restrict__ ws) {
  const int t = threadIdx.x;
  unsigned* mm = reinterpret_cast<unsigned*>(ws + OFF_MM);
  if (t < 64)       mm[t] = 0xFFFFFFFFu; // min keys = +inf
  else if (t < 128) mm[t] = 0u;          // max keys = -inf
  unsigned* bar = reinterpret_cast<unsigned*>(ws + OFF_BARRIER);
  for (int i = t; i < 6144; i += 256) bar[i] = 0u;
}

// ---------------- kernel 1: projection (K-split) + row sqnorms + atomic min/max ----
__global__ __launch_bounds__(256) void proj_kernel(const float* __restrict__ d,
                                                   const float* __restrict__ s,
                                                   const float* __restrict__ M,
                                                   float* __restrict__ ws) {
  const int w    = threadIdx.x >> 6;
  const int lane = threadIdx.x & 63;
  const int r0   = blockIdx.x * 4;

  const float* base;
  if (r0 < ND) base = d + (size_t)r0 * DIN;
  else         base = s + (size_t)(r0 - ND) * DIN;

  const float4* s0 = reinterpret_cast<const float4*>(base + 0 * DIN + w * 192);
  const float4* s1 = reinterpret_cast<const float4*>(base + 1 * DIN + w * 192);
  const float4* s2 = reinterpret_cast<const float4*>(base + 2 * DIN + w * 192);
  const float4* s3 = reinterpret_cast<const float4*>(base + 3 * DIN + w * 192);
  const float* Mw = M + (size_t)(w * 192) * DOUT + lane;

  float a0 = 0.f, a1 = 0.f, a2 = 0.f, a3 = 0.f;
#pragma unroll 4
  for (int kk = 0; kk < 48; ++kk) {
    const float4 r0v = s0[kk];
    const float4 r1v = s1[kk];
    const float4 r2v = s2[kk];
    const float4 r3v = s3[kk];
    const float m0 = Mw[(kk * 4 + 0) * DOUT];
    const float m1 = Mw[(kk * 4 + 1) * DOUT];
    const float m2 = Mw[(kk * 4 + 2) * DOUT];
    const float m3 = Mw[(kk * 4 + 3) * DOUT];
    a0 = fmaf(r0v.x, m0, a0); a0 = fmaf(r0v.y, m1, a0);
    a0 = fmaf(r0v.z, m2, a0); a0 = fmaf(r0v.w, m3, a0);
    a1 = fmaf(r1v.x, m0, a1); a1 = fmaf(r1v.y, m1, a1);
    a1 = fmaf(r1v.z, m2, a1); a1 = fmaf(r1v.w, m3, a1);
    a2 = fmaf(r2v.x, m0, a2); a2 = fmaf(r2v.y, m1, a2);
    a2 = fmaf(r2v.z, m2, a2); a2 = fmaf(r2v.w, m3, a2);
    a3 = fmaf(r3v.x, m0, a3); a3 = fmaf(r3v.y, m1, a3);
    a3 = fmaf(r3v.z, m2, a3); a3 = fmaf(r3v.w, m3, a3);
  }

  __shared__ float part[4][4][64];
  part[w][0][lane] = a0;
  part[w][1][lane] = a1;
  part[w][2][lane] = a2;
  part[w][3][lane] = a3;
  __syncthreads();

  if (w == 0) {
    const float f0 = part[0][0][lane] + part[1][0][lane] + part[2][0][lane] + part[3][0][lane];
    const float f1 = part[0][1][lane] + part[1][1][lane] + part[2][1][lane] + part[3][1][lane];
    const float f2 = part[0][2][lane] + part[1][2][lane] + part[2][2][lane] + part[3][2][lane];
    const float f3 = part[0][3][lane] + part[1][3][lane] + part[2][3][lane] + part[3][3][lane];

    float* xy = ws + OFF_X;
    xy[(size_t)(r0 + 0) * DOUT + lane] = f0;
    xy[(size_t)(r0 + 1) * DOUT + lane] = f1;
    xy[(size_t)(r0 + 2) * DOUT + lane] = f2;
    xy[(size_t)(r0 + 3) * DOUT + lane] = f3;

    const float mn4 = fminf(fminf(f0, f1), fminf(f2, f3));
    const float mx4 = fmaxf(fmaxf(f0, f1), fmaxf(f2, f3));
    unsigned* mm = reinterpret_cast<unsigned*>(ws + OFF_MM);
    atomicMin(mm + lane, fkey(mn4));
    atomicMax(mm + 64 + lane, fkey(mx4));

    float n0 = f0 * f0, n1 = f1 * f1, n2 = f2 * f2, n3 = f3 * f3;
#pragma unroll
    for (int off = 32; off > 0; off >>= 1) {
      n0 += __shfl_xor(n0, off, 64);
      n1 += __shfl_xor(n1, off, 64);
      n2 += __shfl_xor(n2, off, 64);
      n3 += __shfl_xor(n3, off, 64);
    }
    if (lane == 0) {
      float* nrm = ws + OFF_NRM;
      nrm[r0 + 0] = 0.5f * n0;
      nrm[r0 + 1] = 0.5f * n1;
      nrm[r0 + 2] = 0.5f * n2;
      nrm[r0 + 3] = 0.5f * n3;
    }
  }
}

// ---------------- kernel 2: build cost matrices ----------------
__global__ __launch_bounds__(256) void build_cost(float* __restrict__ ws) {
  const int b = blockIdx.x;
  const int tid = threadIdx.x;

  const float* A;
  const float* B;
  const float* nA;
  const float* nB;
  float* Cout;
  float* CoutT = nullptr;
  int ldc, ldcT = 0, ti, tj;

  const float* x = ws + OFF_X;
  const float* y = ws + OFF_X + (size_t)ND * DOUT;
  const float* nx = ws + OFF_NRM;
  const float* ny = ws + OFF_NRM + ND;

  if (b < 512) {
    ti = b >> 4; tj = b & 15;
    A = x; B = y; nA = nx; nB = ny;
    Cout = ws + OFF_CXY; ldc = NS;
    CoutT = ws + OFF_CYX; ldcT = ND;
  } else if (b < 1536) {
    const int bb = b - 512;
    ti = bb >> 5; tj = bb & 31;
    A = x; B = x; nA = nx; nB = nx;
    Cout = ws + OFF_CXX; ldc = ND;
  } else {
    const int bb = b - 1536;
    ti = bb >> 4; tj = bb & 15;
    A = y; B = y; nA = ny; nB = ny;
    Cout = ws + OFF_CYY; ldc = NS;
  }

  __shared__ float Ast[64][68];
  __shared__ float Bst[64][68];

  for (int idx = tid; idx < 64 * 16; idx += 256) {
    const int row = idx >> 4;
    const int c4 = idx & 15;
    const float4 a = reinterpret_cast<const float4*>(A + (size_t)(ti * 64 + row) * DOUT)[c4];
    Ast[c4 * 4 + 0][row] = a.x;
    Ast[c4 * 4 + 1][row] = a.y;
    Ast[c4 * 4 + 2][row] = a.z;
    Ast[c4 * 4 + 3][row] = a.w;
    const float4 bv = reinterpret_cast<const float4*>(B + (size_t)(tj * 64 + row) * DOUT)[c4];
    Bst[c4 * 4 + 0][row] = bv.x;
    Bst[c4 * 4 + 1][row] = bv.y;
    Bst[c4 * 4 + 2][row] = bv.z;
    Bst[c4 * 4 + 3][row] = bv.w;
  }
  __syncthreads();

  const int tr = tid >> 4;
  const int tc = tid & 15;
  float acc[4][4] = {};
#pragma unroll 4
  for (int k = 0; k < 64; ++k) {
    float av[4], bv[4];
#pragma unroll
    for (int i = 0; i < 4; ++i) av[i] = Ast[k][tr * 4 + i];
#pragma unroll
    for (int j = 0; j < 4; ++j) bv[j] = Bst[k][tc * 4 + j];
#pragma unroll
    for (int i = 0; i < 4; ++i)
#pragma unroll
      for (int j = 0; j < 4; ++j) acc[i][j] = fmaf(av[i], bv[j], acc[i][j]);
  }

  float na[4], nb[4];
#pragma unroll
  for (int i = 0; i < 4; ++i) na[i] = nA[ti * 64 + tr * 4 + i];
#pragma unroll
  for (int j = 0; j < 4; ++j) nb[j] = nB[tj * 64 + tc * 4 + j];

#pragma unroll
  for (int i = 0; i < 4; ++i) {
    const int gi = ti * 64 + tr * 4 + i;
    float4 cv;
    cv.x = na[i] + nb[0] - acc[i][0];
    cv.y = na[i] + nb[1] - acc[i][1];
    cv.z = na[i] + nb[2] - acc[i][2];
    cv.w = na[i] + nb[3] - acc[i][3];
    reinterpret_cast<float4*>(Cout + (size_t)gi * ldc + tj * 64 + tc * 4)[0] = cv;
    if (CoutT) {
      const int gj = tj * 64 + tc * 4;
      CoutT[(size_t)(gj + 0) * ldcT + gi] = cv.x;
      CoutT[(size_t)(gj + 1) * ldcT + gi] = cv.y;
      CoutT[(size_t)(gj + 2) * ldcT + gi] = cv.z;
      CoutT[(size_t)(gj + 3) * ldcT + gi] = cv.w;
    }
  }
}

// ---------------- softmin row primitive ----------------
// f_i = -max_j(v) - eps*log( (1/LEN) * sum_j exp((v_j - max)/eps) ), v_j = pot_j - C_ij
template <int LEN, bool USEPOT>
__device__ inline float softmin_row(const float* __restrict__ Crow,
                                    const float* __restrict__ pin,
                                    int lane, float eps, float inv_eps) {
  constexpr int NK = LEN / 256;
  float v[NK * 4];
  float m = -3.4e38f;
#pragma unroll
  for (int k = 0; k < NK; ++k) {
    const float4 c4 = reinterpret_cast<const float4*>(Crow)[k * 64 + lane];
    float4 p4 = make_float4(0.f, 0.f, 0.f, 0.f);
    if (USEPOT) p4 = reinterpret_cast<const float4*>(pin)[k * 64 + lane];
    v[4 * k + 0] = p4.x - c4.x;
    v[4 * k + 1] = p4.y - c4.y;
    v[4 * k + 2] = p4.z - c4.z;
    v[4 * k + 3] = p4.w - c4.w;
    m = fmaxf(m, fmaxf(fmaxf(v[4 * k + 0], v[4 * k + 1]), fmaxf(v[4 * k + 2], v[4 * k + 3])));
  }
#pragma unroll
  for (int off = 32; off > 0; off >>= 1) m = fmaxf(m, __shfl_xor(m, off, 64));
  float ssum = 0.f;
#pragma unroll
  for (int k = 0; k < NK * 4; ++k) ssum += __expf((v[k] - m) * inv_eps);
#pragma unroll
  for (int off = 32; off > 0; off >>= 1) ssum += __shfl_xor(ssum, off, 64);
  return -m - eps * __logf(ssum * (1.0f / (float)LEN));
}

// ---------------- fused sinkhorn: one job ----------------
// Job table: [0,2048) f_ab rows (C_xy, pin=g_ab); [2048,3072) g_ab rows (C_yx, pin=f_ab);
// [3072,5120) f_aa rows (C_xx); [5120,6144) g_bb rows (C_yy).
template <bool USEPOT>
__device__ inline void run_job(const float* __restrict__ ws, const float* __restrict__ potIn,
                               float* __restrict__ potOut, int j, float eps, float inv_eps,
                               bool avg, int lane) {
  const float* Crow;
  const float* pin;
  int outIdx, len;
  if (j < 2048)      { Crow = ws + OFF_CXY + (size_t)j * NS;                        pin = potIn + 2048; outIdx = j;        len = NS; }
  else if (j < 3072) { const int r = j - 2048; Crow = ws + OFF_CYX + (size_t)r * ND; pin = potIn;        outIdx = 2048 + r; len = ND; }
  else if (j < 5120) { const int r = j - 3072; Crow = ws + OFF_CXX + (size_t)r * ND; pin = potIn + 3072; outIdx = 3072 + r; len = ND; }
  else               { const int r = j - 5120; Crow = ws + OFF_CYY + (size_t)r * NS; pin = potIn + 5120; outIdx = 5120 + r; len = NS; }

  float f = (len == NS) ? softmin_row<NS, USEPOT>(Crow, pin, lane, eps, inv_eps)
                        : softmin_row<ND, USEPOT>(Crow, pin, lane, eps, inv_eps);
  if (avg) f = 0.5f * (potIn[outIdx] + f);
  // agent-scope store: bypasses the (non-coherent) local L2, lands at the
  // coherence point (IF$). Readers never have a local L2 copy of this address
  // (single write / single read phase), so plain cached reads are safe.
  if (lane == 0)
    __hip_atomic_store(&potOut[outIdx], f, __ATOMIC_RELAXED, __HIP_MEMORY_SCOPE_AGENT);
}

// ---------------- device-wide barrier (monotone counters, hierarchical) -------------
// 64 arrival lines (stride 64 uints), detector = wave 0 of block 0, 32 gen fan-out lines.
// CRITICAL for performance: poll with RELAXED agent atomics (read through to IF$,
// no cache ops). ACQUIRE polls emit buffer_inv per iteration on gfx95x -> L2
// invalidation storm that evicts the cost matrices continuously (round-6: 6x slowdown,
// 230 MB HBM fetch). The only acq/rel pair kept is the RELEASE on the arrival add
// (orders this block's pot stores before its arrival becomes visible).
__device__ inline void gbarrier(unsigned* __restrict__ bar, unsigned k) {
  __syncthreads();
  if (threadIdx.x == 0) {
    unsigned* cnt = bar + (size_t)(blockIdx.x & 63) * 64;
    __hip_atomic_fetch_add(cnt, 1u, __ATOMIC_RELEASE, __HIP_MEMORY_SCOPE_AGENT);
  }
  if (blockIdx.x == 0) {
    if (threadIdx.x < 64) {
      const unsigned target = (unsigned)NBLK * k;
      for (;;) {
        unsigned v = __hip_atomic_load(bar + (size_t)threadIdx.x * 64,
                                       __ATOMIC_RELAXED, __HIP_MEMORY_SCOPE_AGENT);
        unsigned sum = v;
#pragma unroll
        for (int off = 32; off > 0; off >>= 1)
          sum += (unsigned)__shfl_xor((int)sum, off, 64);
        if (sum >= target) break;
        __builtin_amdgcn_s_sleep(1);
      }
      if (threadIdx.x < 32)
        __hip_atomic_store(bar + 4096 + (size_t)threadIdx.x * 64, k,
                           __ATOMIC_RELAXED, __HIP_MEMORY_SCOPE_AGENT);
    }
  } else {
    if (threadIdx.x == 0) {
      unsigned* gen = bar + 4096 + (size_t)(blockIdx.x & 31) * 64;
      while (__hip_atomic_load(gen, __ATOMIC_RELAXED, __HIP_MEMORY_SCOPE_AGENT) < k)
        __builtin_amdgcn_s_sleep(1);
    }
  }
  __syncthreads();
}

// ---------------- kernel 3: fused sinkhorn (init + 20 steps + final + epilogue) ----
// 1024 blocks x 256. wave = blockIdx*4 + (tid>>6); waves 0..2047 take a second job.
__global__ __launch_bounds__(256, 4) void sinkhorn_fused(float* __restrict__ ws,
                                                         float* __restrict__ out) {
  const int w    = threadIdx.x >> 6;
  const int lane = threadIdx.x & 63;
  const int wave = blockIdx.x * 4 + w;
  float* pots = ws + OFF_POTS;
  unsigned* bar = reinterpret_cast<unsigned*>(ws + OFF_BARRIER);

  // diameter^2 from mm keys (written by proj_kernel, prior dispatch; dedicated slot)
  float diam2;
  {
    const unsigned* mm = reinterpret_cast<const unsigned*>(ws + OFF_MM);
    const float mn = funkey(mm[lane]);
    const float mx = funkey(mm[64 + lane]);
    const float rng = mx - mn;
    float p = rng * rng;
#pragma unroll
    for (int off = 32; off > 0; off >>= 1) p += __shfl_xor(p, off, 64);
    diam2 = p;
  }

  const int j0 = wave;
  const int j1 = (wave < 2048) ? 4096 + wave : -1;
  unsigned bk = 0;

  // ---- init: pots[0], eps0 = max(diam2, blur^2), no pot, no avg
  {
    const float eps = fmaxf(diam2, BLUR2);
    const float ie = 1.0f / eps;
    run_job<false>(ws, pots, pots, j0, eps, ie, false, lane);
    if (j1 >= 0) run_job<false>(ws, pots, pots, j1, eps, ie, false, lane);
  }
  gbarrier(bar, ++bk);

  // ---- 20 scan steps: pots[t] -> pots[t+1], averaged
  for (int t = 0; t < NSTEPS; ++t) {
    const float eps = fmaxf(ldexpf(diam2, -2 * t), BLUR2);
    const float ie = 1.0f / eps;
    const float* pin  = pots + (size_t)t * POT_STRIDE;
    float*       pout = pots + (size_t)(t + 1) * POT_STRIDE;
    run_job<true>(ws, pin, pout, j0, eps, ie, true, lane);
    if (j1 >= 0) run_job<true>(ws, pin, pout, j1, eps, ie, true, lane);
    gbarrier(bar, ++bk);
  }

  // ---- final extrapolation at eps = blur^2
  {
    const float eps = BLUR2;
    const float ie = 1.0f / eps;
    const float* pin  = pots + (size_t)NSTEPS * POT_STRIDE;        // pots[20]
    float*       pout = pots + (size_t)(NSTEPS + 1) * POT_STRIDE;  // pots[21]
    // A: f_ab, f_aa, g_bb (skip g_ab jobs)
    if (j0 < 2048 || j0 >= 3072) run_job<true>(ws, pin, pout, j0, eps, ie, false, lane);
    if (j1 >= 0)                 run_job<true>(ws, pin, pout, j1, eps, ie, false, lane);
    gbarrier(bar, ++bk);
    // B: g_ab from the NEW f_ab (in/out pots[21])
    if (j0 >= 2048 && j0 < 3072) run_job<true>(ws, pout, pout, j0, eps, ie, false, lane);
    gbarrier(bar, ++bk);
  }

  // ---- epilogue: block 0 computes exp(-loss)
  if (blockIdx.x == 0) {
    const float* pot = pots + (size_t)(NSTEPS + 1) * POT_STRIDE;
    const int tid = threadIdx.x;
    float s1 = 0.f, s2 = 0.f;
    for (int i = tid; i < ND; i += 256) s1 += pot[i] - pot[3072 + i];
    for (int j = tid; j < NS; j += 256) s2 += pot[2048 + j] - pot[5120 + j];
    float part = s1 * (1.0f / (float)ND) + s2 * (1.0f / (float)NS);
#pragma unroll
    for (int off = 32; off > 0; off >>= 1) part += __shfl_xor(part, off, 64);
    __shared__ float sp[4];
    if ((tid & 63) == 0) sp[tid >> 6] = part;
    __syncthreads();
    if (tid == 0) out[0] = expf(-(sp[0] + sp[1] + sp[2] + sp[3]));
  }
}

// ---------------- host ----------------
extern "C" void kernel_launch(void* const* d_in, const int* in_sizes, int n_in,
                              void* d_out, int out_size, void* d_ws, size_t ws_size,
                              hipStream_t stream) {
  const float* d = (const float*)d_in[0];
  const float* s = (const float*)d_in[1];
  const float* M = (const float*)d_in[2];
  float* out = (float*)d_out;
  float* ws = (float*)d_ws;

  init_mm<<<1, 256, 0, stream>>>(ws);
  proj_kernel<<<768, 256, 0, stream>>>(d, s, M, ws);
  build_cost<<<1792, 256, 0, stream>>>(ws);
  sinkhorn_fused<<<NBLK, 256, 0, stream>>>(ws, out);
}

// Round 8
// 317.528 us; speedup vs baseline: 4.0422x; 1.4024x over previous
//
#include <hip/hip_runtime.h>
#include <hip/hip_fp16.h>
#include <math.h>

// ---------------- problem constants ----------------
#define ND 2048
#define NS 1024
#define DIN 768
#define DOUT 64
#define NSTEPS 20
static constexpr float BLUR2 = 0.05f * 0.05f; // blur^p, p=2

// ---------------- ws layout ----------------
// float offsets:
#define OFF_X     0u              // 3072*64 = 196608
#define OFF_MM    199680u         // 128 uints: 64 min keys | 64 max keys
#define OFF_POTS  199808u         // 23 gens x 6144 floats (TILDE potentials p~ = p - n)
                                  // gen0 = zpot (-n), gen1 = init, gen2..21 = steps,
                                  // gen22 = final. layout per gen:
                                  // [f_ab 2048 | g_ab 1024 | f_aa 2048 | g_bb 1024]
#define POT_STRIDE 6144u
#define OFF_BARRIER 341120u       // 6144 uints: 64 arrival lines + 32 gen lines
// half offsets (element index into (__half*)ws): fp16 dot matrices
#define H_DXY 694528u             // 2048x1024
#define H_DYX 2791680u            // 1024x2048 (transpose)
#define H_DXX 4888832u            // 2048x2048
#define H_DYY 9083136u            // 1024x1024  (end 10131712 halves ~ 20.3 MB total)

#define NBLK 768    // 3 blocks/CU; guaranteed co-resident via __launch_bounds__(256,3)

// monotone float<->uint key encoding (order-preserving for atomicMin/Max)
__device__ inline unsigned fkey(float f) {
  const unsigned b = __float_as_uint(f);
  return (b & 0x80000000u) ? ~b : (b | 0x80000000u);
}
__device__ inline float funkey(unsigned k) {
  const unsigned b = (k & 0x80000000u) ? (k & 0x7FFFFFFFu) : ~k;
  return __uint_as_float(b);
}

// ---------------- kernel 0: seed min/max keys + zero barrier area ----------------
__global__ __launch_bounds__(256) void init_mm(float* __restrict__ ws) {
  const int t = threadIdx.x;
  unsigned* mm = reinterpret_cast<unsigned*>(ws + OFF_MM);
  if (t < 64)       mm[t] = 0xFFFFFFFFu;
  else if (t < 128) mm[t] = 0u;
  unsigned* bar = reinterpret_cast<unsigned*>(ws + OFF_BARRIER);
  for (int i = t; i < 6144; i += 256) bar[i] = 0u;
}

// ---------------- kernel 1: projection (K-split) + zpot + atomic min/max ----------
__global__ __launch_bounds__(256) void proj_kernel(const float* __restrict__ d,
                                                   const float* __restrict__ s,
                                                   const float* __restrict__ M,
                                                   float* __restrict__ ws) {
  const int w    = threadIdx.x >> 6;
  const int lane = threadIdx.x & 63;
  const int r0   = blockIdx.x * 4;

  const float* base;
  if (r0 < ND) base = d + (size_t)r0 * DIN;
  else         base = s + (size_t)(r0 - ND) * DIN;

  const float4* s0 = reinterpret_cast<const float4*>(base + 0 * DIN + w * 192);
  const float4* s1 = reinterpret_cast<const float4*>(base + 1 * DIN + w * 192);
  const float4* s2 = reinterpret_cast<const float4*>(base + 2 * DIN + w * 192);
  const float4* s3 = reinterpret_cast<const float4*>(base + 3 * DIN + w * 192);
  const float* Mw = M + (size_t)(w * 192) * DOUT + lane;

  float a0 = 0.f, a1 = 0.f, a2 = 0.f, a3 = 0.f;
#pragma unroll 4
  for (int kk = 0; kk < 48; ++kk) {
    const float4 r0v = s0[kk];
    const float4 r1v = s1[kk];
    const float4 r2v = s2[kk];
    const float4 r3v = s3[kk];
    const float m0 = Mw[(kk * 4 + 0) * DOUT];
    const float m1 = Mw[(kk * 4 + 1) * DOUT];
    const float m2 = Mw[(kk * 4 + 2) * DOUT];
    const float m3 = Mw[(kk * 4 + 3) * DOUT];
    a0 = fmaf(r0v.x, m0, a0); a0 = fmaf(r0v.y, m1, a0);
    a0 = fmaf(r0v.z, m2, a0); a0 = fmaf(r0v.w, m3, a0);
    a1 = fmaf(r1v.x, m0, a1); a1 = fmaf(r1v.y, m1, a1);
    a1 = fmaf(r1v.z, m2, a1); a1 = fmaf(r1v.w, m3, a1);
    a2 = fmaf(r2v.x, m0, a2); a2 = fmaf(r2v.y, m1, a2);
    a2 = fmaf(r2v.z, m2, a2); a2 = fmaf(r2v.w, m3, a2);
    a3 = fmaf(r3v.x, m0, a3); a3 = fmaf(r3v.y, m1, a3);
    a3 = fmaf(r3v.z, m2, a3); a3 = fmaf(r3v.w, m3, a3);
  }

  __shared__ float part[4][4][64];
  part[w][0][lane] = a0;
  part[w][1][lane] = a1;
  part[w][2][lane] = a2;
  part[w][3][lane] = a3;
  __syncthreads();

  if (w == 0) {
    const float f0 = part[0][0][lane] + part[1][0][lane] + part[2][0][lane] + part[3][0][lane];
    const float f1 = part[0][1][lane] + part[1][1][lane] + part[2][1][lane] + part[3][1][lane];
    const float f2 = part[0][2][lane] + part[1][2][lane] + part[2][2][lane] + part[3][2][lane];
    const float f3 = part[0][3][lane] + part[1][3][lane] + part[2][3][lane] + part[3][3][lane];

    float* xy = ws + OFF_X;
    xy[(size_t)(r0 + 0) * DOUT + lane] = f0;
    xy[(size_t)(r0 + 1) * DOUT + lane] = f1;
    xy[(size_t)(r0 + 2) * DOUT + lane] = f2;
    xy[(size_t)(r0 + 3) * DOUT + lane] = f3;

    const float mn4 = fminf(fminf(f0, f1), fminf(f2, f3));
    const float mx4 = fmaxf(fmaxf(f0, f1), fmaxf(f2, f3));
    unsigned* mm = reinterpret_cast<unsigned*>(ws + OFF_MM);
    atomicMin(mm + lane, fkey(mn4));
    atomicMax(mm + 64 + lane, fkey(mx4));

    // row sqnorms n = 0.5||row||^2 -> zpot (tilde of zero potential = -n)
    float n0 = f0 * f0, n1 = f1 * f1, n2 = f2 * f2, n3 = f3 * f3;
#pragma unroll
    for (int off = 32; off > 0; off >>= 1) {
      n0 += __shfl_xor(n0, off, 64);
      n1 += __shfl_xor(n1, off, 64);
      n2 += __shfl_xor(n2, off, 64);
      n3 += __shfl_xor(n3, off, 64);
    }
    if (lane == 0) {
      float* zp = ws + OFF_POTS; // gen 0
      const float nn[4] = {0.5f * n0, 0.5f * n1, 0.5f * n2, 0.5f * n3};
#pragma unroll
      for (int k = 0; k < 4; ++k) {
        const int r = r0 + k;
        if (r < ND) { zp[r] = -nn[k];            zp[3072 + r] = -nn[k]; }
        else        { const int j = r - ND; zp[2048 + j] = -nn[k]; zp[5120 + j] = -nn[k]; }
      }
    }
  }
}

// ---------------- kernel 2: build fp16 dot matrices ----------------
// 64x64 tiles. blocks: [0,512) DXY (+ transposed DYX), [512,1536) DXX, [1536,1792) DYY
__global__ __launch_bounds__(256) void build_cost(float* __restrict__ ws) {
  const int b = blockIdx.x;
  const int tid = threadIdx.x;

  const float* A;
  const float* B;
  __half* Dout;
  __half* DoutT = nullptr;
  int ldc, ldcT = 0, ti, tj;

  const float* x = ws + OFF_X;
  const float* y = ws + OFF_X + (size_t)ND * DOUT;
  __half* hws = reinterpret_cast<__half*>(ws);

  if (b < 512) {
    ti = b >> 4; tj = b & 15;
    A = x; B = y;
    Dout = hws + H_DXY; ldc = NS;
    DoutT = hws + H_DYX; ldcT = ND;
  } else if (b < 1536) {
    const int bb = b - 512;
    ti = bb >> 5; tj = bb & 31;
    A = x; B = x;
    Dout = hws + H_DXX; ldc = ND;
  } else {
    const int bb = b - 1536;
    ti = bb >> 4; tj = bb & 15;
    A = y; B = y;
    Dout = hws + H_DYY; ldc = NS;
  }

  __shared__ float Ast[64][68];
  __shared__ float Bst[64][68];

  for (int idx = tid; idx < 64 * 16; idx += 256) {
    const int row = idx >> 4;
    const int c4 = idx & 15;
    const float4 a = reinterpret_cast<const float4*>(A + (size_t)(ti * 64 + row) * DOUT)[c4];
    Ast[c4 * 4 + 0][row] = a.x;
    Ast[c4 * 4 + 1][row] = a.y;
    Ast[c4 * 4 + 2][row] = a.z;
    Ast[c4 * 4 + 3][row] = a.w;
    const float4 bv = reinterpret_cast<const float4*>(B + (size_t)(tj * 64 + row) * DOUT)[c4];
    Bst[c4 * 4 + 0][row] = bv.x;
    Bst[c4 * 4 + 1][row] = bv.y;
    Bst[c4 * 4 + 2][row] = bv.z;
    Bst[c4 * 4 + 3][row] = bv.w;
  }
  __syncthreads();

  const int tr = tid >> 4;
  const int tc = tid & 15;
  float acc[4][4] = {};
#pragma unroll 4
  for (int k = 0; k < 64; ++k) {
    float av[4], bv[4];
#pragma unroll
    for (int i = 0; i < 4; ++i) av[i] = Ast[k][tr * 4 + i];
#pragma unroll
    for (int j = 0; j < 4; ++j) bv[j] = Bst[k][tc * 4 + j];
#pragma unroll
    for (int i = 0; i < 4; ++i)
#pragma unroll
      for (int j = 0; j < 4; ++j) acc[i][j] = fmaf(av[i], bv[j], acc[i][j]);
  }

#pragma unroll
  for (int i = 0; i < 4; ++i) {
    const int gi = ti * 64 + tr * 4 + i;
    const int col = tj * 64 + tc * 4;
    const __half h0 = __float2half_rn(acc[i][0]);
    const __half h1 = __float2half_rn(acc[i][1]);
    const __half h2 = __float2half_rn(acc[i][2]);
    const __half h3 = __float2half_rn(acc[i][3]);
    __half2* dst = reinterpret_cast<__half2*>(Dout + (size_t)gi * ldc + col);
    dst[0] = __halves2half2(h0, h1);
    dst[1] = __halves2half2(h2, h3);
    if (DoutT) {
      DoutT[(size_t)(col + 0) * ldcT + gi] = h0;
      DoutT[(size_t)(col + 1) * ldcT + gi] = h1;
      DoutT[(size_t)(col + 2) * ldcT + gi] = h2;
      DoutT[(size_t)(col + 3) * ldcT + gi] = h3;
    }
  }
}

// ---------------- softmin row primitive (tilde space, fp16 dot) ----------------
// u_j = pot~_j + dot_ij ; returns f~ = -max_u - eps*log( (1/LEN) sum exp((u-max)/eps) )
template <int LEN>
__device__ inline float softmin_fp16(const __half* __restrict__ Dr,
                                     const float* __restrict__ pt,
                                     int lane, float eps, float inv_eps) {
  constexpr int NC = LEN / 512; // chunks of 8 elems/lane
  float u[NC * 8];
  float m = -3.4e38f;
  const float4* df4 = reinterpret_cast<const float4*>(Dr);
  const float4* pf4 = reinterpret_cast<const float4*>(pt);
#pragma unroll
  for (int c = 0; c < NC; ++c) {
    const float4 dv = df4[c * 64 + lane];
    const float4 pa = pf4[c * 128 + lane * 2];
    const float4 pb = pf4[c * 128 + lane * 2 + 1];
    const __half2* h2 = reinterpret_cast<const __half2*>(&dv);
    float* uu = u + c * 8;
    uu[0] = pa.x + __low2float(h2[0]);  uu[1] = pa.y + __high2float(h2[0]);
    uu[2] = pa.z + __low2float(h2[1]);  uu[3] = pa.w + __high2float(h2[1]);
    uu[4] = pb.x + __low2float(h2[2]);  uu[5] = pb.y + __high2float(h2[2]);
    uu[6] = pb.z + __low2float(h2[3]);  uu[7] = pb.w + __high2float(h2[3]);
#pragma unroll
    for (int e = 0; e < 8; ++e) m = fmaxf(m, uu[e]);
  }
#pragma unroll
  for (int off = 32; off > 0; off >>= 1) m = fmaxf(m, __shfl_xor(m, off, 64));
  float ssum = 0.f;
#pragma unroll
  for (int k = 0; k < NC * 8; ++k) ssum += __expf((u[k] - m) * inv_eps);
#pragma unroll
  for (int off = 32; off > 0; off >>= 1) ssum += __shfl_xor(ssum, off, 64);
  return -m - eps * __logf(ssum * (1.0f / (float)LEN));
}

// ---------------- one job (all potentials in tilde space) ----------------
// [0,2048) f_ab (DXY, pin=g~_ab); [2048,3072) g_ab (DYX, pin=f~_ab);
// [3072,5120) f_aa (DXX); [5120,6144) g_bb (DYY).
__device__ inline void run_job(const __half* __restrict__ hws,
                               const float* __restrict__ potIn,
                               float* __restrict__ potOut,
                               int j, float eps, float inv_eps, bool avg, int lane) {
  const __half* Dr;
  const float* pt;
  int outIdx, len;
  if (j < 2048)      { Dr = hws + H_DXY + (size_t)j * NS;                          pt = potIn + 2048; outIdx = j;        len = NS; }
  else if (j < 3072) { const int r = j - 2048; Dr = hws + H_DYX + (size_t)r * ND;  pt = potIn;        outIdx = 2048 + r; len = ND; }
  else if (j < 5120) { const int r = j - 3072; Dr = hws + H_DXX + (size_t)r * ND;  pt = potIn + 3072; outIdx = 3072 + r; len = ND; }
  else               { const int r = j - 5120; Dr = hws + H_DYY + (size_t)r * NS;  pt = potIn + 5120; outIdx = 5120 + r; len = NS; }

  float f = (len == NS) ? softmin_fp16<NS>(Dr, pt, lane, eps, inv_eps)
                        : softmin_fp16<ND>(Dr, pt, lane, eps, inv_eps);
  if (avg) f = 0.5f * (potIn[outIdx] + f);
  // agent-scope store: bypasses the non-coherent local L2, lands at IF$.
  if (lane == 0)
    __hip_atomic_store(&potOut[outIdx], f, __ATOMIC_RELAXED, __HIP_MEMORY_SCOPE_AGENT);
}

// ---------------- device-wide barrier (RELAXED polls; see round-6/7 notes) --------
__device__ inline void gbarrier(unsigned* __restrict__ bar, unsigned k) {
  __syncthreads();
  if (threadIdx.x == 0) {
    unsigned* cnt = bar + (size_t)(blockIdx.x & 63) * 64;
    __hip_atomic_fetch_add(cnt, 1u, __ATOMIC_RELEASE, __HIP_MEMORY_SCOPE_AGENT);
  }
  if (blockIdx.x == 0) {
    if (threadIdx.x < 64) {
      const unsigned target = (unsigned)NBLK * k;
      for (;;) {
        unsigned v = __hip_atomic_load(bar + (size_t)threadIdx.x * 64,
                                       __ATOMIC_RELAXED, __HIP_MEMORY_SCOPE_AGENT);
        unsigned sum = v;
#pragma unroll
        for (int off = 32; off > 0; off >>= 1)
          sum += (unsigned)__shfl_xor((int)sum, off, 64);
        if (sum >= target) break;
        __builtin_amdgcn_s_sleep(1);
      }
      if (threadIdx.x < 32)
        __hip_atomic_store(bar + 4096 + (size_t)threadIdx.x * 64, k,
                           __ATOMIC_RELAXED, __HIP_MEMORY_SCOPE_AGENT);
    }
  } else {
    if (threadIdx.x == 0) {
      unsigned* gen = bar + 4096 + (size_t)(blockIdx.x & 31) * 64;
      while (__hip_atomic_load(gen, __ATOMIC_RELAXED, __HIP_MEMORY_SCOPE_AGENT) < k)
        __builtin_amdgcn_s_sleep(1);
    }
  }
  __syncthreads();
}

// ---------------- kernel 3: fused sinkhorn ----------------
// 768 blocks x 4 waves = 3072 waves. Wave w gets one LONG job (2048 elems) and one
// SHORT job (1024 elems): jL = 2048+w (g_ab rows then f_aa rows),
// jS = w<2048 ? w : 3072+w (f_ab rows then g_bb rows). Perfectly balanced.
__global__ __launch_bounds__(256, 3) void sinkhorn_fused(float* __restrict__ ws,
                                                         float* __restrict__ out) {
  const int w    = threadIdx.x >> 6;
  const int lane = threadIdx.x & 63;
  const int wave = blockIdx.x * 4 + w;
  float* pots = ws + OFF_POTS;
  unsigned* bar = reinterpret_cast<unsigned*>(ws + OFF_BARRIER);
  const __half* hws = reinterpret_cast<const __half*>(ws);

  // diameter^2 from mm keys
  float diam2;
  {
    const unsigned* mm = reinterpret_cast<const unsigned*>(ws + OFF_MM);
    const float mn = funkey(mm[lane]);
    const float mx = funkey(mm[64 + lane]);
    const float rng = mx - mn;
    float p = rng * rng;
#pragma unroll
    for (int off = 32; off > 0; off >>= 1) p += __shfl_xor(p, off, 64);
    diam2 = p;
  }

  const int jL = 2048 + wave;                        // len 2048
  const int jS = (wave < 2048) ? wave : 3072 + wave; // len 1024
  unsigned bk = 0;

  // ---- init: pin = zpot (gen0, = -n), out gen1, no avg
  {
    const float eps = fmaxf(diam2, BLUR2);
    const float ie = 1.0f / eps;
    run_job(hws, pots, pots + POT_STRIDE, jL, eps, ie, false, lane);
    run_job(hws, pots, pots + POT_STRIDE, jS, eps, ie, false, lane);
  }
  gbarrier(bar, ++bk);

  // ---- 20 scan steps: gen(t+1) -> gen(t+2), averaged
  for (int t = 0; t < NSTEPS; ++t) {
    const float eps = fmaxf(ldexpf(diam2, -2 * t), BLUR2);
    const float ie = 1.0f / eps;
    const float* pin  = pots + (size_t)(t + 1) * POT_STRIDE;
    float*       pout = pots + (size_t)(t + 2) * POT_STRIDE;
    run_job(hws, pin, pout, jL, eps, ie, true, lane);
    run_job(hws, pin, pout, jS, eps, ie, true, lane);
    gbarrier(bar, ++bk);
  }

  // ---- final extrapolation at eps = blur^2: gen21 -> gen22
  {
    const float eps = BLUR2;
    const float ie = 1.0f / eps;
    const float* pin  = pots + (size_t)(NSTEPS + 1) * POT_STRIDE; // gen21
    float*       pout = pots + (size_t)(NSTEPS + 2) * POT_STRIDE; // gen22
    // A: f_ab (all jS<2048 or g_bb), f_aa, g_bb -- skip g_ab (jL when wave<1024)
    run_job(hws, pin, pout, jS, eps, ie, false, lane);
    if (wave >= 1024) run_job(hws, pin, pout, jL, eps, ie, false, lane);
    gbarrier(bar, ++bk);
    // B: g_ab from the NEW f~_ab (in/out gen22)
    if (wave < 1024) run_job(hws, pout, pout, jL, eps, ie, false, lane);
    gbarrier(bar, ++bk);
  }

  // ---- epilogue (tilde cancels in the differences)
  if (blockIdx.x == 0) {
    const float* pot = pots + (size_t)(NSTEPS + 2) * POT_STRIDE;
    const int tid = threadIdx.x;
    float s1 = 0.f, s2 = 0.f;
    for (int i = tid; i < ND; i += 256) s1 += pot[i] - pot[3072 + i];
    for (int j = tid; j < NS; j += 256) s2 += pot[2048 + j] - pot[5120 + j];
    float part = s1 * (1.0f / (float)ND) + s2 * (1.0f / (float)NS);
#pragma unroll
    for (int off = 32; off > 0; off >>= 1) part += __shfl_xor(part, off, 64);
    __shared__ float sp[4];
    if ((tid & 63) == 0) sp[tid >> 6] = part;
    __syncthreads();
    if (tid == 0) out[0] = expf(-(sp[0] + sp[1] + sp[2] + sp[3]));
  }
}

// ---------------- host ----------------
extern "C" void kernel_launch(void* const* d_in, const int* in_sizes, int n_in,
                              void* d_out, int out_size, void* d_ws, size_t ws_size,
                              hipStream_t stream) {
  const float* d = (const float*)d_in[0];
  const float* s = (const float*)d_in[1];
  const float* M = (const float*)d_in[2];
  float* out = (float*)d_out;
  float* ws = (float*)d_ws;

  init_mm<<<1, 256, 0, stream>>>(ws);
  proj_kernel<<<768, 256, 0, stream>>>(d, s, M, ws);
  build_cost<<<1792, 256, 0, stream>>>(ws);
  sinkhorn_fused<<<NBLK, 256, 0, stream>>>(ws, out);
}